// Round 1
// baseline (318.281 us; speedup 1.0000x reference)
//
#include <hip/hip_runtime.h>
#include <hip/hip_cooperative_groups.h>

namespace cg = cooperative_groups;

// ContactLoss R7: ONE cooperative dispatch.
//  - Producer phase (grid-stride virtual blocks): raycast VBs (4 points/thread,
//    52B/tri LDS pack, guarded slots, valid folded into invdet=0) + argmin waves.
//  - grid.sync()  -> reduce phase (B*4 blocks, EXACT replica of the old
//    reduce_fin 1024-thread/16-wave summation tree) -> grid.sync() -> block 0
//    finalizes per-batch and global outputs. No workspace counters (poison-safe).

#define RX 0.4395064455f
#define RY 0.617598629942f
#define RZ 0.652231566745f

#define MAXCHUNK 128      // max staged tris (both chunk configs fit)
#define PTS_PER_BLK 1024  // 4 points per thread @ 256 threads

struct Params {
    const float* hand_verts; const int* hand_faces;
    const float* obj_verts;  const int* obj_faces;
    const int* ovsplit; const int* ofsplit;
    int* hitsA;               // [nChA*B*No] pass-A per-chunk hit counts
    int* hitsB;               // [nChB*B*Nh] pass-B per-chunk hit counts
    float* anchor_h; float* anchor_o;
    float* partials;          // [B*16*6] per-(batch, virtual-wave) partial sums
    float* out;
    int B, Nh, Fh, No, Fo;
    int chunkA, chunkB, nChA, nChB;
    int pbA, pbB, blocksA, blocksB, nMinBlk;
};

// ---------------------------------------------------------------------------
// Per-triangle precompute. Identical arithmetic to the absmax-0.0 lineage;
// 'valid' is folded into invdet: invalid => invdet = 0 => u = x*0 = +/-0,
// u > 0 false, tt > 1e-7 false => hit=false, bit-identical to the old flag.
// Pack: f0=(v0,invdet) f1=(e1,px) f2=(e2,py), pz separate (52B/tri).
// ---------------------------------------------------------------------------
__device__ __forceinline__ void tri_pre_one(const float* __restrict__ vb,
                                            const int* __restrict__ f,
                                            float4* o, float* opz) {
#pragma clang fp contract(off)
    int i0 = f[0], i1 = f[1], i2 = f[2];
    float v0x = vb[i0*3+0], v0y = vb[i0*3+1], v0z = vb[i0*3+2];
    float v1x = vb[i1*3+0], v1y = vb[i1*3+1], v1z = vb[i1*3+2];
    float v2x = vb[i2*3+0], v2y = vb[i2*3+1], v2z = vb[i2*3+2];
    float e1x = v1x - v0x, e1y = v1y - v0y, e1z = v1z - v0z;
    float e2x = v2x - v0x, e2y = v2y - v0y, e2z = v2z - v0z;
    float px = RY*e2z - RZ*e2y;
    float py = RZ*e2x - RX*e2z;
    float pz = RX*e2y - RY*e2x;
    float det = (e1x*px + e1y*py) + e1z*pz;       // ((a+b)+c) like np.sum
    float invdet = 1.0f / (det + 1e-8f);          // 0.1*TOL, IEEE div
    if (fabsf(det) < 1e-7f) invdet = 0.0f;        // parallel => no hit, exactly
    o[0] = make_float4(v0x, v0y, v0z, invdet);
    o[1] = make_float4(e1x, e1y, e1z, px);
    o[2] = make_float4(e2x, e2y, e2z, py);
    *opz = pz;
}

// One Möller–Trumbore test — expression tree identical to absmax-0.0 lineage
// (f3.x->f1.w, f3.y->f2.w, f3.z->pz; the valid-flag term is folded upstream).
__device__ __forceinline__ int mt_test(float qx, float qy, float qz,
                                       const float4& f0, const float4& f1,
                                       const float4& f2, float pz) {
#pragma clang fp contract(off)
    float tvx = qx - f0.x, tvy = qy - f0.y, tvz = qz - f0.z;
    float u  = ((tvx*f1.w + tvy*f2.w) + tvz*pz) * f0.w;
    float qvx = tvy*f1.z - tvz*f1.y;
    float qvy = tvz*f1.x - tvx*f1.z;
    float qvz = tvx*f1.y - tvy*f1.x;
    float v  = ((qvx*RX + qvy*RY) + qvz*RZ) * f0.w;
    float tt = ((f2.x*qvx + f2.y*qvy) + f2.z*qvz) * f0.w;
    bool hit = (u > 0.0f) && (u < 1.0f) && (v > 0.0f) &&
               ((u + v) < 1.0f) && (tt > 1e-7f);
    return hit ? 1 : 0;
}

// ---------------------------------------------------------------------------
// One raycast virtual block: chunk staged into LDS, each thread tests FOUR
// points (quarter of the old LDS read traffic per test). Slots 2-4 guarded:
// act masks are monotone, so dead slots skip at wave granularity (execz).
// ---------------------------------------------------------------------------
__device__ __forceinline__ void raycast_vb(const Params& p, int vbid, int tid,
                                           float4* s_tri, float* s_pz) {
#pragma clang fp contract(off)
    const float* pts; const float* tverts; const int* tfaces; int* slots;
    int P, T, Nv, c, pb, b, chunk, tlim, plim;
    if (vbid < p.blocksA) {
        int per_b = p.pbA * p.nChA;
        b  = vbid / per_b;
        int r = vbid - b * per_b;
        c  = r / p.pbA;
        pb = r - c * p.pbA;
        pts = p.obj_verts; tverts = p.hand_verts; tfaces = p.hand_faces;
        slots = p.hitsA;
        P = p.No; T = p.Fh; Nv = p.Nh; chunk = p.chunkA;
        tlim = p.Fh; plim = min(p.No, p.ovsplit[b]);   // invalid pts never read
    } else {
        int j = vbid - p.blocksA;
        int per_b = p.pbB * p.nChB;
        b  = j / per_b;
        int r = j - b * per_b;
        c  = r / p.pbB;
        pb = r - c * p.pbB;
        pts = p.hand_verts; tverts = p.obj_verts; tfaces = p.obj_faces;
        slots = p.hitsB;
        P = p.Nh; T = p.Fo; Nv = p.No; chunk = p.chunkB;
        tlim = min(p.Fo, p.ofsplit[b]); plim = p.Nh;
    }

    int tStart = c * chunk;
    if (tStart >= tlim) return;               // block-uniform (slots unread)
    if (pb * PTS_PER_BLK >= plim) return;     // block-uniform (slots unread)
    int nTri = min(tStart + chunk, tlim) - tStart;

    if (tid < nTri) {
        int t = tStart + tid;
        tri_pre_one(tverts + (size_t)b * Nv * 3,
                    tfaces + ((size_t)b * T + t) * 3,
                    s_tri + (size_t)tid * 3, s_pz + tid);
    }

    int p1 = pb * PTS_PER_BLK + tid;
    int p2 = p1 + 256, p3 = p1 + 512, p4 = p1 + 768;
    bool act1 = p1 < plim, act2 = p2 < plim, act3 = p3 < plim, act4 = p4 < plim;
    float q1x=0.f,q1y=0.f,q1z=0.f, q2x=0.f,q2y=0.f,q2z=0.f;
    float q3x=0.f,q3y=0.f,q3z=0.f, q4x=0.f,q4y=0.f,q4z=0.f;
    if (act1) { const float* q = pts + ((size_t)b*P + p1)*3; q1x=q[0]; q1y=q[1]; q1z=q[2]; }
    if (act2) { const float* q = pts + ((size_t)b*P + p2)*3; q2x=q[0]; q2y=q[1]; q2z=q[2]; }
    if (act3) { const float* q = pts + ((size_t)b*P + p3)*3; q3x=q[0]; q3y=q[1]; q3z=q[2]; }
    if (act4) { const float* q = pts + ((size_t)b*P + p4)*3; q4x=q[0]; q4y=q[1]; q4z=q[2]; }
    __syncthreads();

    if (!act1) return;                        // act masks are monotone
    int c1=0, c2=0, c3=0, c4=0;
    for (int i = 0; i < nTri; ++i) {
        const float4 f0 = s_tri[i*3+0];
        const float4 f1 = s_tri[i*3+1];
        const float4 f2 = s_tri[i*3+2];
        const float pz = s_pz[i];
        c1 += mt_test(q1x,q1y,q1z, f0,f1,f2,pz);
        if (act2) c2 += mt_test(q2x,q2y,q2z, f0,f1,f2,pz);
        if (act3) c3 += mt_test(q3x,q3y,q3z, f0,f1,f2,pz);
        if (act4) c4 += mt_test(q4x,q4y,q4z, f0,f1,f2,pz);
    }
    int* base = slots + ((size_t)(c * p.B + b)) * P;
    base[p1] = c1;                            // plain stores, no atomics
    if (act2) base[p2] = c2;
    if (act3) base[p3] = c3;
    if (act4) base[p4] = c4;
}

// ---------------------------------------------------------------------------
// One argmin wave. Packed (dist<<32)|idx min => np.argmin tie-break. Unchanged.
// ---------------------------------------------------------------------------
__device__ __forceinline__ void min_one(const Params& p, int w, int lane) {
#pragma clang fp contract(off)
    int nHand = p.B * p.Nh;
    const float* refv; const float* loopv; int loopN; float* outp;
    if (w < nHand) {
        int b = w / p.Nh;
        int n = w - b * p.Nh;
        refv  = p.hand_verts + ((size_t)b * p.Nh + n) * 3;
        loopv = p.obj_verts + (size_t)b * p.No * 3;
        loopN = p.ovsplit[b];
        outp  = p.anchor_h + (size_t)b * p.Nh + n;
    } else {
        int j = w - nHand;
        int b = j / p.No;
        int m = j - b * p.No;
        if (m >= p.ovsplit[b]) return;
        refv  = p.obj_verts + ((size_t)b * p.No + m) * 3;
        loopv = p.hand_verts + (size_t)b * p.Nh * 3;
        loopN = p.Nh;
        outp  = p.anchor_o + (size_t)b * p.No + m;
    }
    float hx = refv[0], hy = refv[1], hz = refv[2];
    float rx = (hx*hx + hy*hy) + hz*hz;
    unsigned long long best = ~0ull;
    for (int m = lane; m < loopN; m += 64) {
        float ox = loopv[m*3+0], oy = loopv[m*3+1], oz = loopv[m*3+2];
        float ry = (ox*ox + oy*oy) + oz*oz;
        float zz = (hx*ox + hy*oy) + hz*oz;
        float d = (rx + ry) - 2.0f * zz;
        unsigned long long e = ((unsigned long long)__float_as_uint(d) << 32) | (unsigned)m;
        if (e < best) best = e;
    }
    for (int off = 32; off > 0; off >>= 1) {
        unsigned long long o = __shfl_xor(best, off, 64);
        if (o < best) best = o;
    }
    if (lane == 0) {
        int idx = (best == ~0ull) ? 0 : (int)(best & 0xffffffffu);
        const float* cv = loopv + (size_t)idx * 3;
        float dx = cv[0] - hx, dy = cv[1] - hy, dz = cv[2] - hz;
        *outp = sqrtf((dx*dx + dy*dy) + dz*dz);
    }
}

// ---------------------------------------------------------------------------
// Reduce part: block r handles batch b = r/4, virtual waves (r%4)*4 + wave.
// EXACT replica of old reduce_fin's 1024-thread tree: same per-lane strides,
// same statements, same butterfly. Wave partials -> global, summed in wave
// order by the finalizer (bitwise-identical to old red[16][6] loop).
// ---------------------------------------------------------------------------
__device__ __forceinline__ void reduce_part(const Params& p, int r, int tid) {
    const int b    = r >> 2;
    const int wave = tid >> 6, lane = tid & 63;
    const int wv   = (r & 3) * 4 + wave;       // virtual wave 0..15
    const int vt   = wv * 64 + lane;           // virtual tid  0..1023
    float s0=0.f,s1=0.f,s2=0.f,s3=0.f,s4=0.f,s5=0.f;

    int tlimB = min(p.Fo, p.ofsplit[b]);
    int nCB = (tlimB + p.chunkB - 1) / p.chunkB;        // valid pass-B chunks
    for (int n = vt; n < p.Nh; n += 1024) {
        int par = 0;
        for (int c = 0; c < nCB; ++c)
            par += p.hitsB[((size_t)(c * p.B + b)) * p.Nh + n];
        bool ext = (par & 1) == 0;
        float val = 25.0f * tanhf(p.anchor_h[(size_t)b*p.Nh + n] / 25.0f);
        if (ext) { s0 += val; s1 += 1.0f; } else { s2 += val; s3 += 1.0f; }
    }
    int split = p.ovsplit[b];
    for (int m = vt; m < split; m += 1024) {
        int par = 0;
        for (int c = 0; c < p.nChA; ++c)
            par += p.hitsA[((size_t)(c * p.B + b)) * p.No + m];
        if (par & 1) {                                   // interior & valid
            s4 += 25.0f * tanhf(p.anchor_o[(size_t)b*p.No + m] / 25.0f);
            s5 += 1.0f;
        }
    }
    for (int off = 32; off > 0; off >>= 1) {
        s0 += __shfl_xor(s0, off, 64);
        s1 += __shfl_xor(s1, off, 64);
        s2 += __shfl_xor(s2, off, 64);
        s3 += __shfl_xor(s3, off, 64);
        s4 += __shfl_xor(s4, off, 64);
        s5 += __shfl_xor(s5, off, 64);
    }
    if (lane == 0) {
        float* q = p.partials + ((size_t)(b * 16 + wv)) * 6;
        q[0]=s0; q[1]=s1; q[2]=s2; q[3]=s3; q[4]=s4; q[5]=s5;
    }
}

// ---------------------------------------------------------------------------
// mega (cooperative): producers -> grid.sync -> reduce -> grid.sync -> final.
// ---------------------------------------------------------------------------
__global__ __launch_bounds__(256, 4) void mega(Params p) {
    __shared__ float4 s_tri[MAXCHUNK * 3];
    __shared__ float  s_pz[MAXCHUNK];
    __shared__ float  s_red[8][6];
    const int tid = threadIdx.x;
    const int nRay = p.blocksA + p.blocksB;
    const int nVB  = nRay + p.nMinBlk;
    const int totalMin = p.B * (p.Nh + p.No);

    for (int vb = blockIdx.x; vb < nVB; vb += gridDim.x) {
        if (vb < nRay) {
            __syncthreads();                  // guard s_tri reuse across VBs
            raycast_vb(p, vb, tid, s_tri, s_pz);
        } else {
            int w = (vb - nRay) * 4 + (tid >> 6);
            if (w < totalMin) min_one(p, w, tid & 63);
        }
    }

    cg::this_grid().sync();

    if ((int)blockIdx.x < p.B * 4) reduce_part(p, blockIdx.x, tid);

    cg::this_grid().sync();

    if (blockIdx.x == 0) {
        if (tid < p.B && tid < 8) {
            int b = tid;
            float t0=0.f,t1=0.f,t2=0.f,t3=0.f,t4=0.f,t5=0.f;
            for (int w2 = 0; w2 < 16; ++w2) {   // same wave order as old loop
                const float* q = p.partials + ((size_t)(b * 16 + w2)) * 6;
                t0 += q[0]; t1 += q[1]; t2 += q[2];
                t3 += q[3]; t4 += q[4]; t5 += q[5];
            }
            p.out[2 + b]  = (t1 > 0.f) ? t0 / fmaxf(t1, 1.f) : 0.f;
            float ph      = (t3 > 0.f) ? t2 / fmaxf(t3, 1.f) : 0.f;
            float po      = (t5 > 0.f) ? t4 / fmaxf(t5, 1.f) : 0.f;
            p.out[10 + b] = ph + po;
            s_red[b][0]=t0; s_red[b][1]=t1; s_red[b][2]=t2;
            s_red[b][3]=t3; s_red[b][4]=t4; s_red[b][5]=t5;
        }
        __syncthreads();
        if (tid == 0) {
            float sm=0.f,cm=0.f,sph=0.f,cph=0.f,spo=0.f,cpo=0.f;
            for (int bb = 0; bb < p.B; ++bb) {  // same batch order as old final
                sm  += s_red[bb][0]; cm  += s_red[bb][1]; sph += s_red[bb][2];
                cph += s_red[bb][3]; spo += s_red[bb][4]; cpo += s_red[bb][5];
            }
            float missed = (cm  > 0.f) ? sm  / fmaxf(cm , 1.f) : 0.f;
            float ph     = (cph > 0.f) ? sph / fmaxf(cph, 1.f) : 0.f;
            float po     = (cpo > 0.f) ? spo / fmaxf(cpo, 1.f) : 0.f;
            p.out[0] = missed;
            p.out[1] = ph + po;
        }
    }
}

// ---------------------------------------------------------------------------
extern "C" void kernel_launch(void* const* d_in, const int* in_sizes, int n_in,
                              void* d_out, int out_size, void* d_ws, size_t ws_size,
                              hipStream_t stream) {
    Params p;
    p.hand_verts = (const float*)d_in[0];
    p.hand_faces = (const int*)d_in[1];
    p.obj_verts  = (const float*)d_in[2];
    p.obj_faces  = (const int*)d_in[3];
    p.ovsplit    = (const int*)d_in[4];
    p.ofsplit    = (const int*)d_in[5];
    p.out        = (float*)d_out;

    p.B  = in_sizes[4];
    p.Nh = in_sizes[0] / (3 * p.B);
    p.Fh = in_sizes[1] / (3 * p.B);
    p.No = in_sizes[2] / (3 * p.B);
    p.Fo = in_sizes[3] / (3 * p.B);

    // Chunk config: prefer fine (32/64 chunks -> every coop block gets one
    // raycast VB); fall back to 16/32 (the proven R6 footprint) if ws tight.
    auto conf = [&](int CAt, int CBt, int& chA, int& chB, int& nA, int& nB) -> size_t {
        chA = (p.Fh + CAt - 1) / CAt; if (chA < 1) chA = 1;
        chB = (p.Fo + CBt - 1) / CBt; if (chB < 1) chB = 1;
        nA = (p.Fh + chA - 1) / chA;
        nB = (p.Fo + chB - 1) / chB;
        auto pad = [](size_t x){ return (x + 255) & ~(size_t)255; };
        size_t s = 0;
        s += pad((size_t)nA * p.B * p.No * sizeof(int));
        s += pad((size_t)nB * p.B * p.Nh * sizeof(int));
        s += pad((size_t)p.B * p.Nh * sizeof(float));
        s += pad((size_t)p.B * p.No * sizeof(float));
        s += pad((size_t)p.B * 16 * 6 * sizeof(float));
        return s;
    };
    int chA, chB, nA, nB;
    size_t need = conf(32, 64, chA, chB, nA, nB);
    if (need > ws_size || chA > MAXCHUNK || chB > MAXCHUNK)
        (void)conf(16, 32, chA, chB, nA, nB);
    p.chunkA = chA; p.chunkB = chB; p.nChA = nA; p.nChB = nB;

    p.pbA = (p.No + PTS_PER_BLK - 1) / PTS_PER_BLK;
    p.pbB = (p.Nh + PTS_PER_BLK - 1) / PTS_PER_BLK;
    p.blocksA = p.pbA * p.nChA * p.B;
    p.blocksB = p.pbB * p.nChB * p.B;
    p.nMinBlk = (p.B * (p.Nh + p.No) + 3) / 4;

    char* ws = (char*)d_ws;
    size_t off = 0;
    auto alloc = [&](size_t bytes) -> void* {
        void* q = ws + off;
        off = (off + bytes + 255) & ~(size_t)255;
        return q;
    };
    p.hitsA    = (int*)   alloc((size_t)p.nChA * p.B * p.No * sizeof(int));
    p.hitsB    = (int*)   alloc((size_t)p.nChB * p.B * p.Nh * sizeof(int));
    p.anchor_h = (float*) alloc((size_t)p.B * p.Nh * sizeof(float));
    p.anchor_o = (float*) alloc((size_t)p.B * p.No * sizeof(float));
    p.partials = (float*) alloc((size_t)p.B * 16 * 6 * sizeof(float));

    // Cooperative-safe grid: co-resident capacity from the occupancy API.
    static int cap = 0;
    if (cap == 0) {
        int mbpc = 0;
        if (hipOccupancyMaxActiveBlocksPerMultiprocessor(&mbpc, (const void*)mega,
                                                         256, 0) != hipSuccess ||
            mbpc <= 0)
            mbpc = 4;
        int dev = 0; hipGetDevice(&dev);
        hipDeviceProp_t prop;
        int cus = 256;
        if (hipGetDeviceProperties(&prop, dev) == hipSuccess &&
            prop.multiProcessorCount > 0)
            cus = prop.multiProcessorCount;
        cap = cus * mbpc;
    }
    int nVB = p.blocksA + p.blocksB + p.nMinBlk;
    int grid = (nVB < cap) ? nVB : cap;
    int minGrid = p.B * 4;                    // reduce phase needs B*4 blocks
    if (grid < minGrid) grid = minGrid;

    void* args[] = { &p };
    hipLaunchCooperativeKernel((const void*)mega, dim3(grid), dim3(256),
                               args, 0, stream);
}

// Round 2
// 132.897 us; speedup vs baseline: 2.3950x; 2.3950x over previous
//
#include <hip/hip_runtime.h>

// ContactLoss R8: back to the proven 2-dispatch structure.
//  - mega:       R6 body VERBATIM (64.1 us measured): raycast VBs (2 pts/thread,
//                tri chunk inline into LDS, private hit slots) | argmin blocks.
//  - reduce_fin: WIDENED 8x1024 -> 128x64 blocks using the R7-validated
//                (batch, virtual-wave) decomposition of the exact same
//                summation tree (bit-exact: same virtual tids, same butterfly,
//                same wv-then-batch combine order). Done-counter finalize
//                (R4-proven fence pattern, 128 increments).

#define RX 0.4395064455f
#define RY 0.617598629942f
#define RZ 0.652231566745f

#define MAXCHUNK_F4 512   // LDS float4 slots; >= max(chunkA,chunkB)*4
#define PTS_PER_BLK 512   // 2 points per thread

struct Params {
    const float* hand_verts; const int* hand_faces;
    const float* obj_verts;  const int* obj_faces;
    const int* ovsplit; const int* ofsplit;
    int* hitsA;                // [CA*B*No] pass-A per-chunk hit counts
    int* hitsB;                // [CB*B*Nh] pass-B per-chunk hit counts
    float* anchor_h; float* anchor_o;
    float* partials;           // [B*16*6] per-(batch, virtual-wave) partials
    unsigned int* done;
    float* out;
    int B, Nh, Fh, No, Fo;
    int pbA, CA, chunkA, blocksA;
    int pbB, CB, chunkB, blocksB;
};

// ---------------------------------------------------------------------------
// Per-triangle precompute (identical arithmetic to the absmax-0.0 lineage).
// ---------------------------------------------------------------------------
__device__ __forceinline__ void tri_pre_one(const float* __restrict__ vb,
                                            const int* __restrict__ f,
                                            float4* o) {
#pragma clang fp contract(off)
    int i0 = f[0], i1 = f[1], i2 = f[2];
    float v0x = vb[i0*3+0], v0y = vb[i0*3+1], v0z = vb[i0*3+2];
    float v1x = vb[i1*3+0], v1y = vb[i1*3+1], v1z = vb[i1*3+2];
    float v2x = vb[i2*3+0], v2y = vb[i2*3+1], v2z = vb[i2*3+2];
    float e1x = v1x - v0x, e1y = v1y - v0y, e1z = v1z - v0z;
    float e2x = v2x - v0x, e2y = v2y - v0y, e2z = v2z - v0z;
    float px = RY*e2z - RZ*e2y;
    float py = RZ*e2x - RX*e2z;
    float pz = RX*e2y - RY*e2x;
    float det = (e1x*px + e1y*py) + e1z*pz;       // ((a+b)+c) like np.sum
    float invdet = 1.0f / (det + 1e-8f);          // 0.1*TOL, IEEE div
    bool valid = !(fabsf(det) < 1e-7f);
    o[0] = make_float4(v0x, v0y, v0z, invdet);
    o[1] = make_float4(e1x, e1y, e1z, valid ? 1.0f : 0.0f);
    o[2] = make_float4(e2x, e2y, e2z, 0.0f);
    o[3] = make_float4(px,  py,  pz,  0.0f);
}

// One Möller–Trumbore test (expression tree identical to absmax-0.0 lineage).
__device__ __forceinline__ int mt_test(float qx, float qy, float qz,
                                       const float4& f0, const float4& f1,
                                       const float4& f2, const float4& f3) {
#pragma clang fp contract(off)
    float tvx = qx - f0.x, tvy = qy - f0.y, tvz = qz - f0.z;
    float u  = ((tvx*f3.x + tvy*f3.y) + tvz*f3.z) * f0.w;
    float qvx = tvy*f1.z - tvz*f1.y;
    float qvy = tvz*f1.x - tvx*f1.z;
    float qvz = tvx*f1.y - tvy*f1.x;
    float v  = ((qvx*RX + qvy*RY) + qvz*RZ) * f0.w;
    float tt = ((f2.x*qvx + f2.y*qvy) + f2.z*qvz) * f0.w;
    bool hit = (u > 0.0f) && (u < 1.0f) && (v > 0.0f) &&
               ((u + v) < 1.0f) && (tt > 1e-7f) && (f1.w != 0.0f);
    return hit ? 1 : 0;
}

// ---------------------------------------------------------------------------
// One raycast virtual block: triangle chunk built inline into LDS, each
// thread tests TWO points (halves LDS read traffic per test).
// ---------------------------------------------------------------------------
__device__ __forceinline__ void raycast_vb(const Params& p, int vbid, int tid,
                                           float4* s_tri) {
#pragma clang fp contract(off)
    const float* pts; const float* tverts; const int* tfaces; int* slots;
    int P, T, Nv, c, pb, b, chunk, tlim, plim;
    if (vbid < p.blocksA) {
        int per_b = p.pbA * p.CA;
        b  = vbid / per_b;
        int r = vbid - b * per_b;
        c  = r / p.pbA;
        pb = r - c * p.pbA;
        pts = p.obj_verts; tverts = p.hand_verts; tfaces = p.hand_faces;
        slots = p.hitsA;
        P = p.No; T = p.Fh; Nv = p.Nh; chunk = p.chunkA;
        tlim = p.Fh; plim = min(p.No, p.ovsplit[b]);   // invalid pts never read
    } else {
        int j = vbid - p.blocksA;
        int per_b = p.pbB * p.CB;
        b  = j / per_b;
        int r = j - b * per_b;
        c  = r / p.pbB;
        pb = r - c * p.pbB;
        pts = p.hand_verts; tverts = p.obj_verts; tfaces = p.obj_faces;
        slots = p.hitsB;
        P = p.Nh; T = p.Fo; Nv = p.No; chunk = p.chunkB;
        tlim = min(p.Fo, p.ofsplit[b]); plim = p.Nh;
    }

    int tStart = c * chunk;
    if (tStart >= tlim) return;               // block-uniform (slots unread)
    if (pb * PTS_PER_BLK >= plim) return;     // block-uniform (slots unread)
    int nTri = min(tStart + chunk, tlim) - tStart;

    if (tid < nTri) {
        int t = tStart + tid;
        tri_pre_one(tverts + (size_t)b * Nv * 3,
                    tfaces + ((size_t)b * T + t) * 3,
                    s_tri + (size_t)tid * 4);
    }

    int p1 = pb * PTS_PER_BLK + tid;
    int p2 = p1 + 256;
    bool act1 = p1 < plim, act2 = p2 < plim;
    float q1x = 0.f, q1y = 0.f, q1z = 0.f;
    float q2x = 0.f, q2y = 0.f, q2z = 0.f;
    if (act1) {
        const float* q = pts + ((size_t)b * P + p1) * 3;
        q1x = q[0]; q1y = q[1]; q1z = q[2];
    }
    if (act2) {
        const float* q = pts + ((size_t)b * P + p2) * 3;
        q2x = q[0]; q2y = q[1]; q2z = q[2];
    }
    __syncthreads();

    if (!act1) return;                        // act1 false => act2 false
    int cnt1 = 0, cnt2 = 0;
    for (int i = 0; i < nTri; ++i) {
        const float4 f0 = s_tri[(i<<2)+0];
        const float4 f1 = s_tri[(i<<2)+1];
        const float4 f2 = s_tri[(i<<2)+2];
        const float4 f3 = s_tri[(i<<2)+3];
        cnt1 += mt_test(q1x, q1y, q1z, f0, f1, f2, f3);
        cnt2 += mt_test(q2x, q2y, q2z, f0, f1, f2, f3);
    }
    int* base = slots + ((size_t)(c * p.B + b)) * P;
    base[p1] = cnt1;                          // plain stores, no atomics
    if (act2) base[p2] = cnt2;
}

// ---------------------------------------------------------------------------
// One argmin wave. Packed (dist<<32)|idx min => np.argmin tie-break.
// ---------------------------------------------------------------------------
__device__ __forceinline__ void min_one(const Params& p, int w, int lane) {
#pragma clang fp contract(off)
    int nHand = p.B * p.Nh;
    const float* refv; const float* loopv; int loopN; float* outp;
    if (w < nHand) {
        int b = w / p.Nh;
        int n = w - b * p.Nh;
        refv  = p.hand_verts + ((size_t)b * p.Nh + n) * 3;
        loopv = p.obj_verts + (size_t)b * p.No * 3;
        loopN = p.ovsplit[b];
        outp  = p.anchor_h + (size_t)b * p.Nh + n;
    } else {
        int j = w - nHand;
        int b = j / p.No;
        int m = j - b * p.No;
        if (m >= p.ovsplit[b]) return;
        refv  = p.obj_verts + ((size_t)b * p.No + m) * 3;
        loopv = p.hand_verts + (size_t)b * p.Nh * 3;
        loopN = p.Nh;
        outp  = p.anchor_o + (size_t)b * p.No + m;
    }
    float hx = refv[0], hy = refv[1], hz = refv[2];
    float rx = (hx*hx + hy*hy) + hz*hz;
    unsigned long long best = ~0ull;
    for (int m = lane; m < loopN; m += 64) {
        float ox = loopv[m*3+0], oy = loopv[m*3+1], oz = loopv[m*3+2];
        float ry = (ox*ox + oy*oy) + oz*oz;
        float zz = (hx*ox + hy*oy) + hz*oz;
        float d = (rx + ry) - 2.0f * zz;
        unsigned long long e = ((unsigned long long)__float_as_uint(d) << 32) | (unsigned)m;
        if (e < best) best = e;
    }
    for (int off = 32; off > 0; off >>= 1) {
        unsigned long long o = __shfl_xor(best, off, 64);
        if (o < best) best = o;
    }
    if (lane == 0) {
        int idx = (best == ~0ull) ? 0 : (int)(best & 0xffffffffu);
        const float* cv = loopv + (size_t)idx * 3;
        float dx = cv[0] - hx, dy = cv[1] - hy, dz = cv[2] - hz;
        *outp = sqrtf((dx*dx + dy*dy) + dz*dz);
    }
}

// ---------------------------------------------------------------------------
// mega: [raycast VBs | argmin blocks] — no tail sync; resets done counter.
// (R6 body verbatim.)
// ---------------------------------------------------------------------------
__global__ __launch_bounds__(256) void mega(Params p) {
    __shared__ float4 s_tri[MAXCHUNK_F4];
    const int tid = threadIdx.x;
    const int bid = blockIdx.x;
    if (bid == 0 && tid == 0) *p.done = 0u;   // visible to reduce_fin at boundary
    const int nRay = p.blocksA + p.blocksB;
    if (bid < nRay) {
        raycast_vb(p, bid, tid, s_tri);
    } else {
        int w = (bid - nRay) * 4 + (tid >> 6);
        if (w < p.B * (p.Nh + p.No)) min_one(p, w, tid & 63);
    }
}

// ---------------------------------------------------------------------------
// reduce_fin: 128 single-wave blocks. Block r = (batch b = r>>4, virtual wave
// wv = r&15) of the old 1024-thread tree: virtual tid vt = wv*64+lane walks
// the SAME element sets with the SAME strides; butterfly identical; partials
// combined in wv-then-batch order by the last-done block (R7-validated
// bit-exact decomposition; R4-proven done-counter fence pattern).
// ---------------------------------------------------------------------------
__global__ __launch_bounds__(64) void reduce_fin(Params p) {
    const int r    = blockIdx.x;
    const int b    = r >> 4;
    const int wv   = r & 15;
    const int lane = threadIdx.x;
    const int vt   = wv * 64 + lane;          // virtual tid 0..1023
    float s0=0.f,s1=0.f,s2=0.f,s3=0.f,s4=0.f,s5=0.f;

    int tlimB = min(p.Fo, p.ofsplit[b]);
    int nCB = (tlimB + p.chunkB - 1) / p.chunkB;        // valid pass-B chunks
    for (int n = vt; n < p.Nh; n += 1024) {
        int par = 0;
        for (int c = 0; c < nCB; ++c)
            par += p.hitsB[((size_t)(c * p.B + b)) * p.Nh + n];
        bool ext = (par & 1) == 0;
        float val = 25.0f * tanhf(p.anchor_h[(size_t)b*p.Nh + n] / 25.0f);
        if (ext) { s0 += val; s1 += 1.0f; } else { s2 += val; s3 += 1.0f; }
    }
    int split = p.ovsplit[b];
    for (int m = vt; m < split; m += 1024) {
        int par = 0;
        for (int c = 0; c < p.CA; ++c)
            par += p.hitsA[((size_t)(c * p.B + b)) * p.No + m];
        if (par & 1) {                                   // interior & valid
            s4 += 25.0f * tanhf(p.anchor_o[(size_t)b*p.No + m] / 25.0f);
            s5 += 1.0f;
        }
    }
    for (int off = 32; off > 0; off >>= 1) {
        s0 += __shfl_xor(s0, off, 64);
        s1 += __shfl_xor(s1, off, 64);
        s2 += __shfl_xor(s2, off, 64);
        s3 += __shfl_xor(s3, off, 64);
        s4 += __shfl_xor(s4, off, 64);
        s5 += __shfl_xor(s5, off, 64);
    }

    __shared__ bool s_last;
    if (lane == 0) {
        float* q = p.partials + ((size_t)(b * 16 + wv)) * 6;
        q[0]=s0; q[1]=s1; q[2]=s2; q[3]=s3; q[4]=s4; q[5]=s5;
        __threadfence();                     // release partials
        unsigned int old = atomicAdd(p.done, 1u);
        s_last = (old == (unsigned int)(gridDim.x - 1));
    }
    __syncthreads();
    if (!s_last) return;
    __threadfence();                         // acquire others' partials

    __shared__ float s_red[16][6];
    if (lane < p.B && lane < 16) {
        int bb = lane;
        float t0=0.f,t1=0.f,t2=0.f,t3=0.f,t4=0.f,t5=0.f;
        for (int w2 = 0; w2 < 16; ++w2) {     // same wave order as old loop
            const float* q = p.partials + ((size_t)(bb * 16 + w2)) * 6;
            t0 += q[0]; t1 += q[1]; t2 += q[2];
            t3 += q[3]; t4 += q[4]; t5 += q[5];
        }
        p.out[2 + bb]  = (t1 > 0.f) ? t0 / fmaxf(t1, 1.f) : 0.f;
        float ph       = (t3 > 0.f) ? t2 / fmaxf(t3, 1.f) : 0.f;
        float po       = (t5 > 0.f) ? t4 / fmaxf(t5, 1.f) : 0.f;
        p.out[10 + bb] = ph + po;
        s_red[bb][0]=t0; s_red[bb][1]=t1; s_red[bb][2]=t2;
        s_red[bb][3]=t3; s_red[bb][4]=t4; s_red[bb][5]=t5;
    }
    __syncthreads();
    if (lane == 0) {
        float sm=0.f,cm=0.f,sph=0.f,cph=0.f,spo=0.f,cpo=0.f;
        for (int bb = 0; bb < p.B; ++bb) {    // same batch order as old final
            sm  += s_red[bb][0]; cm  += s_red[bb][1]; sph += s_red[bb][2];
            cph += s_red[bb][3]; spo += s_red[bb][4]; cpo += s_red[bb][5];
        }
        float missed = (cm  > 0.f) ? sm  / fmaxf(cm , 1.f) : 0.f;
        float ph     = (cph > 0.f) ? sph / fmaxf(cph, 1.f) : 0.f;
        float po     = (cpo > 0.f) ? spo / fmaxf(cpo, 1.f) : 0.f;
        p.out[0] = missed;
        p.out[1] = ph + po;
    }
}

// ---------------------------------------------------------------------------
extern "C" void kernel_launch(void* const* d_in, const int* in_sizes, int n_in,
                              void* d_out, int out_size, void* d_ws, size_t ws_size,
                              hipStream_t stream) {
    Params p;
    p.hand_verts = (const float*)d_in[0];
    p.hand_faces = (const int*)d_in[1];
    p.obj_verts  = (const float*)d_in[2];
    p.obj_faces  = (const int*)d_in[3];
    p.ovsplit    = (const int*)d_in[4];
    p.ofsplit    = (const int*)d_in[5];
    p.out        = (float*)d_out;

    p.B  = in_sizes[4];
    p.Nh = in_sizes[0] / (3 * p.B);
    p.Fh = in_sizes[1] / (3 * p.B);
    p.No = in_sizes[2] / (3 * p.B);
    p.Fo = in_sizes[3] / (3 * p.B);

    p.CA = 16; p.CB = 32;
    p.chunkA = (p.Fh + p.CA - 1) / p.CA;       // 97  for Fh=1538 (388 f4 <= 512)
    p.chunkB = (p.Fo + p.CB - 1) / p.CB;       // 125 for Fo=4000 (500 f4 <= 512)
    p.pbA = (p.No + PTS_PER_BLK - 1) / PTS_PER_BLK;   // 4
    p.pbB = (p.Nh + PTS_PER_BLK - 1) / PTS_PER_BLK;   // 2
    p.blocksA = p.pbA * p.CA * p.B;            // 512
    p.blocksB = p.pbB * p.CB * p.B;            // 512

    char* ws = (char*)d_ws;
    size_t off = 0;
    auto alloc = [&](size_t bytes) -> void* {
        void* q = ws + off;
        off = (off + bytes + 255) & ~(size_t)255;
        return q;
    };
    p.hitsA    = (int*)   alloc((size_t)p.CA * p.B * p.No * sizeof(int));
    p.hitsB    = (int*)   alloc((size_t)p.CB * p.B * p.Nh * sizeof(int));
    p.anchor_h = (float*) alloc((size_t)p.B * p.Nh * sizeof(float));
    p.anchor_o = (float*) alloc((size_t)p.B * p.No * sizeof(float));
    p.partials = (float*) alloc((size_t)p.B * 16 * 6 * sizeof(float));
    p.done     = (unsigned int*)alloc(sizeof(unsigned int));

    int totalMin   = p.B * (p.Nh + p.No);
    int nMinBlocks = (totalMin + 3) / 4;       // 4 argmin waves per block
    int grid = p.blocksA + p.blocksB + nMinBlocks;

    mega<<<grid, 256, 0, stream>>>(p);
    reduce_fin<<<p.B * 16, 64, 0, stream>>>(p);
}

// Round 3
// 132.238 us; speedup vs baseline: 2.4069x; 1.0050x over previous
//
#include <hip/hip_runtime.h>

// ContactLoss R9: 2-dispatch structure (R8) + mega VALU trim.
//  - mega: R6 raycast body with two bit-exact instruction cuts:
//      (1) valid-flag folded into invdet=0 (R7-validated, absmax 0.0):
//          invalid => u = x*0 = +/-0 => u>0 false, tt>1e-7 false == old flag.
//      (2) wave-uniform __any(act2) split: waves with no live second point
//          run a single-point loop (halves the ~11% pass-B tail waste and
//          pass-A low-split tails). Lanes with act2 false inside the dual
//          loop compute-and-discard exactly as before => bit-identical.
//  - reduce_fin: R8 verbatim (128x64 blocks, (batch, virtual-wave) bit-exact
//    decomposition, done-counter + fence finalize).

#define RX 0.4395064455f
#define RY 0.617598629942f
#define RZ 0.652231566745f

#define MAXCHUNK_F4 512   // LDS float4 slots; >= max(chunkA,chunkB)*4
#define PTS_PER_BLK 512   // 2 points per thread

struct Params {
    const float* hand_verts; const int* hand_faces;
    const float* obj_verts;  const int* obj_faces;
    const int* ovsplit; const int* ofsplit;
    int* hitsA;                // [CA*B*No] pass-A per-chunk hit counts
    int* hitsB;                // [CB*B*Nh] pass-B per-chunk hit counts
    float* anchor_h; float* anchor_o;
    float* partials;           // [B*16*6] per-(batch, virtual-wave) partials
    unsigned int* done;
    float* out;
    int B, Nh, Fh, No, Fo;
    int pbA, CA, chunkA, blocksA;
    int pbB, CB, chunkB, blocksB;
};

// ---------------------------------------------------------------------------
// Per-triangle precompute (identical arithmetic to the absmax-0.0 lineage;
// valid folded into invdet=0 — R7-validated bit-exact).
// ---------------------------------------------------------------------------
__device__ __forceinline__ void tri_pre_one(const float* __restrict__ vb,
                                            const int* __restrict__ f,
                                            float4* o) {
#pragma clang fp contract(off)
    int i0 = f[0], i1 = f[1], i2 = f[2];
    float v0x = vb[i0*3+0], v0y = vb[i0*3+1], v0z = vb[i0*3+2];
    float v1x = vb[i1*3+0], v1y = vb[i1*3+1], v1z = vb[i1*3+2];
    float v2x = vb[i2*3+0], v2y = vb[i2*3+1], v2z = vb[i2*3+2];
    float e1x = v1x - v0x, e1y = v1y - v0y, e1z = v1z - v0z;
    float e2x = v2x - v0x, e2y = v2y - v0y, e2z = v2z - v0z;
    float px = RY*e2z - RZ*e2y;
    float py = RZ*e2x - RX*e2z;
    float pz = RX*e2y - RY*e2x;
    float det = (e1x*px + e1y*py) + e1z*pz;       // ((a+b)+c) like np.sum
    float invdet = 1.0f / (det + 1e-8f);          // 0.1*TOL, IEEE div
    if (fabsf(det) < 1e-7f) invdet = 0.0f;        // parallel => no hit, exactly
    o[0] = make_float4(v0x, v0y, v0z, invdet);
    o[1] = make_float4(e1x, e1y, e1z, 0.0f);
    o[2] = make_float4(e2x, e2y, e2z, 0.0f);
    o[3] = make_float4(px,  py,  pz,  0.0f);
}

// One Möller–Trumbore test (expression tree identical to absmax-0.0 lineage;
// the valid-flag conjunct is folded into invdet upstream).
__device__ __forceinline__ int mt_test(float qx, float qy, float qz,
                                       const float4& f0, const float4& f1,
                                       const float4& f2, const float4& f3) {
#pragma clang fp contract(off)
    float tvx = qx - f0.x, tvy = qy - f0.y, tvz = qz - f0.z;
    float u  = ((tvx*f3.x + tvy*f3.y) + tvz*f3.z) * f0.w;
    float qvx = tvy*f1.z - tvz*f1.y;
    float qvy = tvz*f1.x - tvx*f1.z;
    float qvz = tvx*f1.y - tvy*f1.x;
    float v  = ((qvx*RX + qvy*RY) + qvz*RZ) * f0.w;
    float tt = ((f2.x*qvx + f2.y*qvy) + f2.z*qvz) * f0.w;
    bool hit = (u > 0.0f) && (u < 1.0f) && (v > 0.0f) &&
               ((u + v) < 1.0f) && (tt > 1e-7f);
    return hit ? 1 : 0;
}

// ---------------------------------------------------------------------------
// One raycast virtual block: triangle chunk built inline into LDS, each
// thread tests TWO points. Waves with no live second point (__any(act2)
// false — wave-uniform) run a single-point loop instead.
// ---------------------------------------------------------------------------
__device__ __forceinline__ void raycast_vb(const Params& p, int vbid, int tid,
                                           float4* s_tri) {
#pragma clang fp contract(off)
    const float* pts; const float* tverts; const int* tfaces; int* slots;
    int P, T, Nv, c, pb, b, chunk, tlim, plim;
    if (vbid < p.blocksA) {
        int per_b = p.pbA * p.CA;
        b  = vbid / per_b;
        int r = vbid - b * per_b;
        c  = r / p.pbA;
        pb = r - c * p.pbA;
        pts = p.obj_verts; tverts = p.hand_verts; tfaces = p.hand_faces;
        slots = p.hitsA;
        P = p.No; T = p.Fh; Nv = p.Nh; chunk = p.chunkA;
        tlim = p.Fh; plim = min(p.No, p.ovsplit[b]);   // invalid pts never read
    } else {
        int j = vbid - p.blocksA;
        int per_b = p.pbB * p.CB;
        b  = j / per_b;
        int r = j - b * per_b;
        c  = r / p.pbB;
        pb = r - c * p.pbB;
        pts = p.hand_verts; tverts = p.obj_verts; tfaces = p.obj_faces;
        slots = p.hitsB;
        P = p.Nh; T = p.Fo; Nv = p.No; chunk = p.chunkB;
        tlim = min(p.Fo, p.ofsplit[b]); plim = p.Nh;
    }

    int tStart = c * chunk;
    if (tStart >= tlim) return;               // block-uniform (slots unread)
    if (pb * PTS_PER_BLK >= plim) return;     // block-uniform (slots unread)
    int nTri = min(tStart + chunk, tlim) - tStart;

    if (tid < nTri) {
        int t = tStart + tid;
        tri_pre_one(tverts + (size_t)b * Nv * 3,
                    tfaces + ((size_t)b * T + t) * 3,
                    s_tri + (size_t)tid * 4);
    }

    int p1 = pb * PTS_PER_BLK + tid;
    int p2 = p1 + 256;
    bool act1 = p1 < plim, act2 = p2 < plim;
    float q1x = 0.f, q1y = 0.f, q1z = 0.f;
    float q2x = 0.f, q2y = 0.f, q2z = 0.f;
    if (act1) {
        const float* q = pts + ((size_t)b * P + p1) * 3;
        q1x = q[0]; q1y = q[1]; q1z = q[2];
    }
    if (act2) {
        const float* q = pts + ((size_t)b * P + p2) * 3;
        q2x = q[0]; q2y = q[1]; q2z = q[2];
    }
    __syncthreads();

    if (!act1) return;                        // act1 false => act2 false
    int cnt1 = 0, cnt2 = 0;
    if (__any(act2)) {
        // Dual-point loop: identical to R6/R8 codegen; act2-false lanes
        // compute-and-discard cnt2 exactly as before (store is guarded).
        for (int i = 0; i < nTri; ++i) {
            const float4 f0 = s_tri[(i<<2)+0];
            const float4 f1 = s_tri[(i<<2)+1];
            const float4 f2 = s_tri[(i<<2)+2];
            const float4 f3 = s_tri[(i<<2)+3];
            cnt1 += mt_test(q1x, q1y, q1z, f0, f1, f2, f3);
            cnt2 += mt_test(q2x, q2y, q2z, f0, f1, f2, f3);
        }
    } else {
        // No live second point anywhere in this wave: half the work.
        for (int i = 0; i < nTri; ++i) {
            const float4 f0 = s_tri[(i<<2)+0];
            const float4 f1 = s_tri[(i<<2)+1];
            const float4 f2 = s_tri[(i<<2)+2];
            const float4 f3 = s_tri[(i<<2)+3];
            cnt1 += mt_test(q1x, q1y, q1z, f0, f1, f2, f3);
        }
    }
    int* base = slots + ((size_t)(c * p.B + b)) * P;
    base[p1] = cnt1;                          // plain stores, no atomics
    if (act2) base[p2] = cnt2;
}

// ---------------------------------------------------------------------------
// One argmin wave. Packed (dist<<32)|idx min => np.argmin tie-break.
// ---------------------------------------------------------------------------
__device__ __forceinline__ void min_one(const Params& p, int w, int lane) {
#pragma clang fp contract(off)
    int nHand = p.B * p.Nh;
    const float* refv; const float* loopv; int loopN; float* outp;
    if (w < nHand) {
        int b = w / p.Nh;
        int n = w - b * p.Nh;
        refv  = p.hand_verts + ((size_t)b * p.Nh + n) * 3;
        loopv = p.obj_verts + (size_t)b * p.No * 3;
        loopN = p.ovsplit[b];
        outp  = p.anchor_h + (size_t)b * p.Nh + n;
    } else {
        int j = w - nHand;
        int b = j / p.No;
        int m = j - b * p.No;
        if (m >= p.ovsplit[b]) return;
        refv  = p.obj_verts + ((size_t)b * p.No + m) * 3;
        loopv = p.hand_verts + (size_t)b * p.Nh * 3;
        loopN = p.Nh;
        outp  = p.anchor_o + (size_t)b * p.No + m;
    }
    float hx = refv[0], hy = refv[1], hz = refv[2];
    float rx = (hx*hx + hy*hy) + hz*hz;
    unsigned long long best = ~0ull;
    for (int m = lane; m < loopN; m += 64) {
        float ox = loopv[m*3+0], oy = loopv[m*3+1], oz = loopv[m*3+2];
        float ry = (ox*ox + oy*oy) + oz*oz;
        float zz = (hx*ox + hy*oy) + hz*oz;
        float d = (rx + ry) - 2.0f * zz;
        unsigned long long e = ((unsigned long long)__float_as_uint(d) << 32) | (unsigned)m;
        if (e < best) best = e;
    }
    for (int off = 32; off > 0; off >>= 1) {
        unsigned long long o = __shfl_xor(best, off, 64);
        if (o < best) best = o;
    }
    if (lane == 0) {
        int idx = (best == ~0ull) ? 0 : (int)(best & 0xffffffffu);
        const float* cv = loopv + (size_t)idx * 3;
        float dx = cv[0] - hx, dy = cv[1] - hy, dz = cv[2] - hz;
        *outp = sqrtf((dx*dx + dy*dy) + dz*dz);
    }
}

// ---------------------------------------------------------------------------
// mega: [raycast VBs | argmin blocks] — no tail sync; resets done counter.
// ---------------------------------------------------------------------------
__global__ __launch_bounds__(256) void mega(Params p) {
    __shared__ float4 s_tri[MAXCHUNK_F4];
    const int tid = threadIdx.x;
    const int bid = blockIdx.x;
    if (bid == 0 && tid == 0) *p.done = 0u;   // visible to reduce_fin at boundary
    const int nRay = p.blocksA + p.blocksB;
    if (bid < nRay) {
        raycast_vb(p, bid, tid, s_tri);
    } else {
        int w = (bid - nRay) * 4 + (tid >> 6);
        if (w < p.B * (p.Nh + p.No)) min_one(p, w, tid & 63);
    }
}

// ---------------------------------------------------------------------------
// reduce_fin: 128 single-wave blocks (R8 verbatim). Block r = (batch b=r>>4,
// virtual wave wv=r&15) of the old 1024-thread tree; bit-exact decomposition;
// done-counter + fence finalize.
// ---------------------------------------------------------------------------
__global__ __launch_bounds__(64) void reduce_fin(Params p) {
    const int r    = blockIdx.x;
    const int b    = r >> 4;
    const int wv   = r & 15;
    const int lane = threadIdx.x;
    const int vt   = wv * 64 + lane;          // virtual tid 0..1023
    float s0=0.f,s1=0.f,s2=0.f,s3=0.f,s4=0.f,s5=0.f;

    int tlimB = min(p.Fo, p.ofsplit[b]);
    int nCB = (tlimB + p.chunkB - 1) / p.chunkB;        // valid pass-B chunks
    for (int n = vt; n < p.Nh; n += 1024) {
        int par = 0;
        for (int c = 0; c < nCB; ++c)
            par += p.hitsB[((size_t)(c * p.B + b)) * p.Nh + n];
        bool ext = (par & 1) == 0;
        float val = 25.0f * tanhf(p.anchor_h[(size_t)b*p.Nh + n] / 25.0f);
        if (ext) { s0 += val; s1 += 1.0f; } else { s2 += val; s3 += 1.0f; }
    }
    int split = p.ovsplit[b];
    for (int m = vt; m < split; m += 1024) {
        int par = 0;
        for (int c = 0; c < p.CA; ++c)
            par += p.hitsA[((size_t)(c * p.B + b)) * p.No + m];
        if (par & 1) {                                   // interior & valid
            s4 += 25.0f * tanhf(p.anchor_o[(size_t)b*p.No + m] / 25.0f);
            s5 += 1.0f;
        }
    }
    for (int off = 32; off > 0; off >>= 1) {
        s0 += __shfl_xor(s0, off, 64);
        s1 += __shfl_xor(s1, off, 64);
        s2 += __shfl_xor(s2, off, 64);
        s3 += __shfl_xor(s3, off, 64);
        s4 += __shfl_xor(s4, off, 64);
        s5 += __shfl_xor(s5, off, 64);
    }

    __shared__ bool s_last;
    if (lane == 0) {
        float* q = p.partials + ((size_t)(b * 16 + wv)) * 6;
        q[0]=s0; q[1]=s1; q[2]=s2; q[3]=s3; q[4]=s4; q[5]=s5;
        __threadfence();                     // release partials
        unsigned int old = atomicAdd(p.done, 1u);
        s_last = (old == (unsigned int)(gridDim.x - 1));
    }
    __syncthreads();
    if (!s_last) return;
    __threadfence();                         // acquire others' partials

    __shared__ float s_red[16][6];
    if (lane < p.B && lane < 16) {
        int bb = lane;
        float t0=0.f,t1=0.f,t2=0.f,t3=0.f,t4=0.f,t5=0.f;
        for (int w2 = 0; w2 < 16; ++w2) {     // same wave order as old loop
            const float* q = p.partials + ((size_t)(bb * 16 + w2)) * 6;
            t0 += q[0]; t1 += q[1]; t2 += q[2];
            t3 += q[3]; t4 += q[4]; t5 += q[5];
        }
        p.out[2 + bb]  = (t1 > 0.f) ? t0 / fmaxf(t1, 1.f) : 0.f;
        float ph       = (t3 > 0.f) ? t2 / fmaxf(t3, 1.f) : 0.f;
        float po       = (t5 > 0.f) ? t4 / fmaxf(t5, 1.f) : 0.f;
        p.out[10 + bb] = ph + po;
        s_red[bb][0]=t0; s_red[bb][1]=t1; s_red[bb][2]=t2;
        s_red[bb][3]=t3; s_red[bb][4]=t4; s_red[bb][5]=t5;
    }
    __syncthreads();
    if (lane == 0) {
        float sm=0.f,cm=0.f,sph=0.f,cph=0.f,spo=0.f,cpo=0.f;
        for (int bb = 0; bb < p.B; ++bb) {    // same batch order as old final
            sm  += s_red[bb][0]; cm  += s_red[bb][1]; sph += s_red[bb][2];
            cph += s_red[bb][3]; spo += s_red[bb][4]; cpo += s_red[bb][5];
        }
        float missed = (cm  > 0.f) ? sm  / fmaxf(cm , 1.f) : 0.f;
        float ph     = (cph > 0.f) ? sph / fmaxf(cph, 1.f) : 0.f;
        float po     = (cpo > 0.f) ? spo / fmaxf(cpo, 1.f) : 0.f;
        p.out[0] = missed;
        p.out[1] = ph + po;
    }
}

// ---------------------------------------------------------------------------
extern "C" void kernel_launch(void* const* d_in, const int* in_sizes, int n_in,
                              void* d_out, int out_size, void* d_ws, size_t ws_size,
                              hipStream_t stream) {
    Params p;
    p.hand_verts = (const float*)d_in[0];
    p.hand_faces = (const int*)d_in[1];
    p.obj_verts  = (const float*)d_in[2];
    p.obj_faces  = (const int*)d_in[3];
    p.ovsplit    = (const int*)d_in[4];
    p.ofsplit    = (const int*)d_in[5];
    p.out        = (float*)d_out;

    p.B  = in_sizes[4];
    p.Nh = in_sizes[0] / (3 * p.B);
    p.Fh = in_sizes[1] / (3 * p.B);
    p.No = in_sizes[2] / (3 * p.B);
    p.Fo = in_sizes[3] / (3 * p.B);

    p.CA = 16; p.CB = 32;
    p.chunkA = (p.Fh + p.CA - 1) / p.CA;       // 97  for Fh=1538 (388 f4 <= 512)
    p.chunkB = (p.Fo + p.CB - 1) / p.CB;       // 125 for Fo=4000 (500 f4 <= 512)
    p.pbA = (p.No + PTS_PER_BLK - 1) / PTS_PER_BLK;   // 4
    p.pbB = (p.Nh + PTS_PER_BLK - 1) / PTS_PER_BLK;   // 2
    p.blocksA = p.pbA * p.CA * p.B;            // 512
    p.blocksB = p.pbB * p.CB * p.B;            // 512

    char* ws = (char*)d_ws;
    size_t off = 0;
    auto alloc = [&](size_t bytes) -> void* {
        void* q = ws + off;
        off = (off + bytes + 255) & ~(size_t)255;
        return q;
    };
    p.hitsA    = (int*)   alloc((size_t)p.CA * p.B * p.No * sizeof(int));
    p.hitsB    = (int*)   alloc((size_t)p.CB * p.B * p.Nh * sizeof(int));
    p.anchor_h = (float*) alloc((size_t)p.B * p.Nh * sizeof(float));
    p.anchor_o = (float*) alloc((size_t)p.B * p.No * sizeof(float));
    p.partials = (float*) alloc((size_t)p.B * 16 * 6 * sizeof(float));
    p.done     = (unsigned int*)alloc(sizeof(unsigned int));

    int totalMin   = p.B * (p.Nh + p.No);
    int nMinBlocks = (totalMin + 3) / 4;       // 4 argmin waves per block
    int grid = p.blocksA + p.blocksB + nMinBlocks;

    mega<<<grid, 256, 0, stream>>>(p);
    reduce_fin<<<p.B * 16, 64, 0, stream>>>(p);
}